// Round 4
// baseline (971.252 us; speedup 1.0000x reference)
//
#include <hip/hip_runtime.h>

// GaussianActionDistGenerator: dual projection (mean/std) + masked tanh-clipped scores.
// B=8, L=2048, D=128. out = (s_mean [B,L,L], s_std [B,L,L]) f32, concatenated.

#define B_ 8
#define L_ 2048
#define D_ 128
#define NP (B_ * L_ * D_)            // 2,097,152 elems per projection array
#define BLL ((size_t)B_ * L_ * L_)   // 33,554,432 elems per output tensor

typedef __attribute__((ext_vector_type(8))) short short8;
typedef __attribute__((ext_vector_type(4))) float f32x4;
typedef __attribute__((ext_vector_type(16))) float f32x16;

__device__ __forceinline__ unsigned short f32_bf16(float x) {
  unsigned u = __float_as_uint(x);
  u += 0x7FFF + ((u >> 16) & 1);   // round-to-nearest-even on the bf16 boundary
  return (unsigned short)(u >> 16);
}
__device__ __forceinline__ float bf16_f32(unsigned short h) {
  return __uint_as_float(((unsigned)h) << 16);
}
__device__ __forceinline__ float fast_tanh(float x) {
  // tanh(x) = 1 - 2/(exp(2x)+1); saturates correctly at +/-inf
  float e = __expf(2.0f * x);
  return 1.0f - 2.0f * __builtin_amdgcn_rcpf(e + 1.0f);
}

// ---------------------------------------------------------------------------
// Kernel 0: transpose weights [k][n] -> [n][k] and split f32 -> bf16 hi/lo.
// WT layout (ushort): WT[p*16384 + n*128 + k] (hi), WT[(4+p)*16384 + ...] (lo)
// ---------------------------------------------------------------------------
__global__ __launch_bounds__(256) void prep_w(
    const float* __restrict__ w0, const float* __restrict__ w1,
    const float* __restrict__ w2, const float* __restrict__ w3,
    unsigned short* __restrict__ WT) {
  int p = blockIdx.x;
  const float* W = (p == 0) ? w0 : (p == 1) ? w1 : (p == 2) ? w2 : w3;
  int idx = blockIdx.y * 256 + threadIdx.x;   // 0..16383 = k*128+n
  int k = idx >> 7, n = idx & 127;
  float v = W[idx];
  unsigned short h = f32_bf16(v);
  WT[p * 16384 + n * 128 + k] = h;
  WT[(4 + p) * 16384 + n * 128 + k] = f32_bf16(v - bf16_f32(h));
}

// ---------------------------------------------------------------------------
// Kernel 0b: split query/key f32 -> bf16 hi/lo planes, fully coalesced.
// XS layout (ushort): [query_hi NP][query_lo NP][key_hi NP][key_lo NP]
// ---------------------------------------------------------------------------
__global__ __launch_bounds__(256) void split_x(
    const float* __restrict__ q, const float* __restrict__ k,
    unsigned short* __restrict__ XS) {
  size_t idx = ((size_t)blockIdx.x * 256 + threadIdx.x) * 8;
  const float* src;
  unsigned short* dh;
  if (idx < (size_t)NP) {
    src = q + idx;
    dh = XS + idx;
  } else {
    src = k + (idx - NP);
    dh = XS + 2 * (size_t)NP + (idx - NP);
  }
  unsigned short* dl = dh + NP;
  f32x4 v0 = *(const f32x4*)src;
  f32x4 v1 = *(const f32x4*)(src + 4);
  short8 h, l;
#pragma unroll
  for (int j = 0; j < 4; j++) {
    unsigned short hh = f32_bf16(v0[j]);
    h[j] = (short)hh;
    l[j] = (short)f32_bf16(v0[j] - bf16_f32(hh));
    unsigned short hg = f32_bf16(v1[j]);
    h[4 + j] = (short)hg;
    l[4 + j] = (short)f32_bf16(v1[j] - bf16_f32(hg));
  }
  *(short8*)dh = h;
  *(short8*)dl = l;
}

// ---------------------------------------------------------------------------
// Kernel 1: projections. y=0: query -> qm (p0), qs (p2); y=1: key -> km (p1), ks (p3).
// Each block: 64 tokens, 4 waves x 16 tokens. MFMA 16x16x32 bf16, hi/lo 3-product split.
// A-fragments come from pre-split XS (16B/lane loads).
// Output P (ushort): P[p*NP + token*128 + d] hi, P[(4+p)*NP + ...] lo.
// ---------------------------------------------------------------------------
__global__ __launch_bounds__(256) void proj_k(
    const unsigned short* __restrict__ XS,
    const float* __restrict__ bqm, const float* __restrict__ bkm,
    const float* __restrict__ bqs, const float* __restrict__ bks,
    const unsigned short* __restrict__ WT,
    unsigned short* __restrict__ P) {
  const int y = blockIdx.y;
  const unsigned short* Xh = XS + (size_t)y * 2 * NP;
  const unsigned short* Xl = Xh + NP;
  const float* bias_m = y ? bkm : bqm;
  const float* bias_s = y ? bks : bqs;
  const int pm = y, ps = y + 2;
  const int wave = threadIdx.x >> 6, lane = threadIdx.x & 63;
  const int lr = lane & 15, kq = lane >> 4;
  const int rowbase = blockIdx.x * 64 + wave * 16;

  const unsigned short* wmh = WT + pm * 16384;
  const unsigned short* wml = WT + (4 + pm) * 16384;
  const unsigned short* wsh = WT + ps * 16384;
  const unsigned short* wsl = WT + (4 + ps) * 16384;

  f32x4 accm[8], accs[8];
#pragma unroll
  for (int i = 0; i < 8; i++) {
    accm[i] = f32x4{0.f, 0.f, 0.f, 0.f};
    accs[i] = f32x4{0.f, 0.f, 0.f, 0.f};
  }

#pragma unroll
  for (int ks = 0; ks < 4; ks++) {
    const int koff = ks * 32 + kq * 8;
    const int ao = (rowbase + lr) * D_ + koff;
    short8 a_hi = *(const short8*)(Xh + ao);
    short8 a_lo = *(const short8*)(Xl + ao);
#pragma unroll
    for (int nt = 0; nt < 8; nt++) {
      const int wo = (nt * 16 + lr) * 128 + koff;
      short8 bh = *(const short8*)(wmh + wo);
      short8 bl = *(const short8*)(wml + wo);
      accm[nt] = __builtin_amdgcn_mfma_f32_16x16x32_bf16(a_hi, bh, accm[nt], 0, 0, 0);
      accm[nt] = __builtin_amdgcn_mfma_f32_16x16x32_bf16(a_lo, bh, accm[nt], 0, 0, 0);
      accm[nt] = __builtin_amdgcn_mfma_f32_16x16x32_bf16(a_hi, bl, accm[nt], 0, 0, 0);
      short8 ch = *(const short8*)(wsh + wo);
      short8 cl = *(const short8*)(wsl + wo);
      accs[nt] = __builtin_amdgcn_mfma_f32_16x16x32_bf16(a_hi, ch, accs[nt], 0, 0, 0);
      accs[nt] = __builtin_amdgcn_mfma_f32_16x16x32_bf16(a_lo, ch, accs[nt], 0, 0, 0);
      accs[nt] = __builtin_amdgcn_mfma_f32_16x16x32_bf16(a_hi, cl, accs[nt], 0, 0, 0);
    }
  }

  unsigned short* Pmh = P + pm * NP;
  unsigned short* Pml = P + (4 + pm) * NP;
  unsigned short* Psh = P + ps * NP;
  unsigned short* Psl = P + (4 + ps) * NP;
#pragma unroll
  for (int nt = 0; nt < 8; nt++) {
    const int col = nt * 16 + lr;
    const float bm = bias_m[col];
    const float bs = bias_s[col];
#pragma unroll
    for (int r = 0; r < 4; r++) {
      const int token = rowbase + kq * 4 + r;
      const int o = token * D_ + col;
      float vm = accm[nt][r] + bm;
      unsigned short h = f32_bf16(vm);
      Pmh[o] = h;
      Pml[o] = f32_bf16(vm - bf16_f32(h));
      float vs = accs[nt][r] + bs;
      unsigned short g = f32_bf16(vs);
      Psh[o] = g;
      Psl[o] = f32_bf16(vs - bf16_f32(g));
    }
  }
}

// ---------------------------------------------------------------------------
// Kernel 2 (v3): masked scores, NO LDS. 32x32x16 MFMA: per-reg scalar stores
// are naturally full-line (2 x 128B per instruction). Mean and std computed
// sequentially to halve accumulator pressure (target <=128 VGPR -> 4 blk/CU).
// Mask bits cached in a u64 between passes. XCD-aware: batch = bid & 7.
// ---------------------------------------------------------------------------
__global__ __launch_bounds__(256, 4) void scores_k(
    const unsigned short* __restrict__ P,
    const int* __restrict__ mask,
    float* __restrict__ out) {
  const int bid = blockIdx.x;
  const int z = bid & 7;             // batch == XCD slot (L2 locality: 8 MB/batch panels)
  const int idx = bid >> 3;
  const int q0 = (idx >> 4) * 128, c0 = (idx & 15) * 128;
  const int wave = threadIdx.x >> 6, lane = threadIdx.x & 63;
  const int wr = wave >> 1, wc = wave & 1;
  const int lc = lane & 31, lh = lane >> 5;

  const float rs = 0.08838834764831845f;  // 1/sqrt(128)
  unsigned long long mbits = 0ull;

  for (int p = 0; p < 2; ++p) {          // p=0: mean (planes 0,1); p=1: std (planes 2,3)
    const unsigned short* Qh = P + (size_t)(2 * p) * NP;
    const unsigned short* Ql = Qh + 4 * (size_t)NP;
    const unsigned short* Kh = P + (size_t)(2 * p + 1) * NP;
    const unsigned short* Kl = Kh + 4 * (size_t)NP;

    const int qr0 = (z * L_ + q0 + wr * 64) * D_;
    const int cr0 = (z * L_ + c0 + wc * 64) * D_;

    f32x16 acc[2][2];
#pragma unroll
    for (int i = 0; i < 2; i++)
#pragma unroll
      for (int j = 0; j < 2; j++)
#pragma unroll
        for (int r = 0; r < 16; r++) acc[i][j][r] = 0.0f;

#pragma unroll
    for (int kk = 0; kk < 8; ++kk) {     // K=16 per MFMA, D=128 -> 8 steps
      const int ko = kk * 16 + lh * 8;
      short8 ah[2], al[2], bh[2], bl[2];
#pragma unroll
      for (int t = 0; t < 2; t++) {
        const int aoff = qr0 + (t * 32 + lc) * D_ + ko;
        ah[t] = *(const short8*)(Qh + aoff);
        al[t] = *(const short8*)(Ql + aoff);
        const int boff = cr0 + (t * 32 + lc) * D_ + ko;
        bh[t] = *(const short8*)(Kh + boff);
        bl[t] = *(const short8*)(Kl + boff);
      }
#pragma unroll
      for (int tr = 0; tr < 2; tr++)
#pragma unroll
        for (int tc = 0; tc < 2; tc++) {
          acc[tr][tc] = __builtin_amdgcn_mfma_f32_32x32x16_bf16(ah[tr], bh[tc], acc[tr][tc], 0, 0, 0);
          acc[tr][tc] = __builtin_amdgcn_mfma_f32_32x32x16_bf16(al[tr], bh[tc], acc[tr][tc], 0, 0, 0);
          acc[tr][tc] = __builtin_amdgcn_mfma_f32_32x32x16_bf16(ah[tr], bl[tc], acc[tr][tc], 0, 0, 0);
        }
    }

    // Epilogue: C/D layout col=lane&31, row=(r&3)+8*(r>>2)+4*(lane>>5).
    // Per (tr,tc,r): one scalar store = 2 full 128B lines across the wave.
#pragma unroll
    for (int tr = 0; tr < 2; tr++) {
      const int growb = q0 + wr * 64 + tr * 32 + 4 * lh;
#pragma unroll
      for (int tc = 0; tc < 2; tc++) {
        const int gcol = c0 + wc * 64 + tc * 32 + lc;
#pragma unroll
        for (int r = 0; r < 16; r++) {
          const int grow = growb + (r & 3) + 8 * (r >> 2);
          const size_t a = ((size_t)(z * L_ + grow)) * L_ + gcol;
          const float t = fast_tanh(acc[tr][tc][r] * rs);
          const int bi = (tr * 2 + tc) * 16 + r;
          if (p == 0) {
            const int mv = mask[a];
            out[a] = mv ? (0.5f * t + 0.5f) : 0.0f;
            if (mv) mbits |= (1ull << bi);
          } else {
            const bool mv = (mbits >> bi) & 1ull;
            out[BLL + a] = mv ? (4.0f * t - 6.0f) : -10.0f;
          }
        }
      }
    }
  }
}

extern "C" void kernel_launch(void* const* d_in, const int* in_sizes, int n_in,
                              void* d_out, int out_size, void* d_ws, size_t ws_size,
                              hipStream_t stream) {
  const float* query = (const float*)d_in[0];
  const float* key   = (const float*)d_in[1];
  const int*   mask  = (const int*)d_in[2];
  const float* Wqm   = (const float*)d_in[3];
  const float* bqm   = (const float*)d_in[4];
  const float* Wkm   = (const float*)d_in[5];
  const float* bkm   = (const float*)d_in[6];
  const float* Wqs   = (const float*)d_in[7];
  const float* bqs   = (const float*)d_in[8];
  const float* Wks   = (const float*)d_in[9];
  const float* bks   = (const float*)d_in[10];

  unsigned short* P  = (unsigned short*)d_ws;       // 8 * NP ushorts = 33.55 MB
  unsigned short* WT = P + 8 * (size_t)NP;          // 8 * 16384 ushorts
  unsigned short* XS = WT + 8 * 16384;              // 4 * NP ushorts = 16.8 MB

  prep_w<<<dim3(4, 64), 256, 0, stream>>>(Wqm, Wkm, Wqs, Wks, WT);
  split_x<<<dim3(2048), 256, 0, stream>>>(query, key, XS);
  proj_k<<<dim3(256, 2), 256, 0, stream>>>(XS, bqm, bkm, bqs, bks, WT, P);
  scores_k<<<dim3(2048), 256, 0, stream>>>(P, mask, (float*)d_out);
}

// Round 5
// 614.369 us; speedup vs baseline: 1.5809x; 1.5809x over previous
//
#include <hip/hip_runtime.h>

// GaussianActionDistGenerator: dual projection (mean/std) + masked tanh-clipped scores.
// B=8, L=2048, D=128. out = (s_mean [B,L,L], s_std [B,L,L]) f32, concatenated.

#define B_ 8
#define L_ 2048
#define D_ 128
#define NP (B_ * L_ * D_)            // 2,097,152 elems per projection array
#define BLL ((size_t)B_ * L_ * L_)   // 33,554,432 elems per output tensor

typedef __attribute__((ext_vector_type(8))) short short8;
typedef __attribute__((ext_vector_type(4))) float f32x4;

__device__ __forceinline__ unsigned short f32_bf16(float x) {
  unsigned u = __float_as_uint(x);
  u += 0x7FFF + ((u >> 16) & 1);   // round-to-nearest-even on the bf16 boundary
  return (unsigned short)(u >> 16);
}
__device__ __forceinline__ float bf16_f32(unsigned short h) {
  return __uint_as_float(((unsigned)h) << 16);
}
__device__ __forceinline__ float fast_tanh(float x) {
  // tanh(x) = 1 - 2/(exp(2x)+1); saturates correctly at +/-inf
  float e = __expf(2.0f * x);
  return 1.0f - 2.0f * __builtin_amdgcn_rcpf(e + 1.0f);
}

// ---------------------------------------------------------------------------
// Kernel 0: transpose weights [k][n] -> [n][k] and split f32 -> bf16 hi/lo.
// ---------------------------------------------------------------------------
__global__ __launch_bounds__(256) void prep_w(
    const float* __restrict__ w0, const float* __restrict__ w1,
    const float* __restrict__ w2, const float* __restrict__ w3,
    unsigned short* __restrict__ WT) {
  int p = blockIdx.x;
  const float* W = (p == 0) ? w0 : (p == 1) ? w1 : (p == 2) ? w2 : w3;
  int idx = blockIdx.y * 256 + threadIdx.x;   // 0..16383 = k*128+n
  int k = idx >> 7, n = idx & 127;
  float v = W[idx];
  unsigned short h = f32_bf16(v);
  WT[p * 16384 + n * 128 + k] = h;
  WT[(4 + p) * 16384 + n * 128 + k] = f32_bf16(v - bf16_f32(h));
}

// ---------------------------------------------------------------------------
// Kernel 0b: split query/key f32 -> bf16 hi/lo planes, fully coalesced.
// XS layout (ushort): [query_hi NP][query_lo NP][key_hi NP][key_lo NP]
// ---------------------------------------------------------------------------
__global__ __launch_bounds__(256) void split_x(
    const float* __restrict__ q, const float* __restrict__ k,
    unsigned short* __restrict__ XS) {
  size_t idx = ((size_t)blockIdx.x * 256 + threadIdx.x) * 8;
  const float* src;
  unsigned short* dh;
  if (idx < (size_t)NP) {
    src = q + idx;
    dh = XS + idx;
  } else {
    src = k + (idx - NP);
    dh = XS + 2 * (size_t)NP + (idx - NP);
  }
  unsigned short* dl = dh + NP;
  f32x4 v0 = *(const f32x4*)src;
  f32x4 v1 = *(const f32x4*)(src + 4);
  short8 h, l;
#pragma unroll
  for (int j = 0; j < 4; j++) {
    unsigned short hh = f32_bf16(v0[j]);
    h[j] = (short)hh;
    l[j] = (short)f32_bf16(v0[j] - bf16_f32(hh));
    unsigned short hg = f32_bf16(v1[j]);
    h[4 + j] = (short)hg;
    l[4 + j] = (short)f32_bf16(v1[j] - bf16_f32(hg));
  }
  *(short8*)dh = h;
  *(short8*)dl = l;
}

// ---------------------------------------------------------------------------
// Kernel 1: projections. y=0: query -> qm (p0), qs (p2); y=1: key -> km, ks.
// MFMA 16x16x32 bf16, hi/lo 3-product split. A from pre-split XS.
// Output P (ushort): P[p*NP + token*128 + d] hi, P[(4+p)*NP + ...] lo.
// ---------------------------------------------------------------------------
__global__ __launch_bounds__(256) void proj_k(
    const unsigned short* __restrict__ XS,
    const float* __restrict__ bqm, const float* __restrict__ bkm,
    const float* __restrict__ bqs, const float* __restrict__ bks,
    const unsigned short* __restrict__ WT,
    unsigned short* __restrict__ P) {
  const int y = blockIdx.y;
  const unsigned short* Xh = XS + (size_t)y * 2 * NP;
  const unsigned short* Xl = Xh + NP;
  const float* bias_m = y ? bkm : bqm;
  const float* bias_s = y ? bks : bqs;
  const int pm = y, ps = y + 2;
  const int wave = threadIdx.x >> 6, lane = threadIdx.x & 63;
  const int lr = lane & 15, kq = lane >> 4;
  const int rowbase = blockIdx.x * 64 + wave * 16;

  const unsigned short* wmh = WT + pm * 16384;
  const unsigned short* wml = WT + (4 + pm) * 16384;
  const unsigned short* wsh = WT + ps * 16384;
  const unsigned short* wsl = WT + (4 + ps) * 16384;

  f32x4 accm[8], accs[8];
#pragma unroll
  for (int i = 0; i < 8; i++) {
    accm[i] = f32x4{0.f, 0.f, 0.f, 0.f};
    accs[i] = f32x4{0.f, 0.f, 0.f, 0.f};
  }

#pragma unroll
  for (int ks = 0; ks < 4; ks++) {
    const int koff = ks * 32 + kq * 8;
    const int ao = (rowbase + lr) * D_ + koff;
    short8 a_hi = *(const short8*)(Xh + ao);
    short8 a_lo = *(const short8*)(Xl + ao);
#pragma unroll
    for (int nt = 0; nt < 8; nt++) {
      const int wo = (nt * 16 + lr) * 128 + koff;
      short8 bh = *(const short8*)(wmh + wo);
      short8 bl = *(const short8*)(wml + wo);
      accm[nt] = __builtin_amdgcn_mfma_f32_16x16x32_bf16(a_hi, bh, accm[nt], 0, 0, 0);
      accm[nt] = __builtin_amdgcn_mfma_f32_16x16x32_bf16(a_lo, bh, accm[nt], 0, 0, 0);
      accm[nt] = __builtin_amdgcn_mfma_f32_16x16x32_bf16(a_hi, bl, accm[nt], 0, 0, 0);
      short8 ch = *(const short8*)(wsh + wo);
      short8 cl = *(const short8*)(wsl + wo);
      accs[nt] = __builtin_amdgcn_mfma_f32_16x16x32_bf16(a_hi, ch, accs[nt], 0, 0, 0);
      accs[nt] = __builtin_amdgcn_mfma_f32_16x16x32_bf16(a_lo, ch, accs[nt], 0, 0, 0);
      accs[nt] = __builtin_amdgcn_mfma_f32_16x16x32_bf16(a_hi, cl, accs[nt], 0, 0, 0);
    }
  }

  unsigned short* Pmh = P + pm * NP;
  unsigned short* Pml = P + (4 + pm) * NP;
  unsigned short* Psh = P + ps * NP;
  unsigned short* Psl = P + (4 + ps) * NP;
#pragma unroll
  for (int nt = 0; nt < 8; nt++) {
    const int col = nt * 16 + lr;
    const float bm = bias_m[col];
    const float bs = bias_s[col];
#pragma unroll
    for (int r = 0; r < 4; r++) {
      const int token = rowbase + kq * 4 + r;
      const int o = token * D_ + col;
      float vm = accm[nt][r] + bm;
      unsigned short h = f32_bf16(vm);
      Pmh[o] = h;
      Pml[o] = f32_bf16(vm - bf16_f32(h));
      float vs = accs[nt][r] + bs;
      unsigned short g = f32_bf16(vs);
      Psh[o] = g;
      Psl[o] = f32_bf16(vs - bf16_f32(g));
    }
  }
}

// ---------------------------------------------------------------------------
// Kernel 2 (v4): masked scores. 16x16x32 MFMA, 4 waves 2x2 (wc=wave&1 cols,
// wr=wave>>1 rows), 128x128 tile/block. Sequential mean/std passes (64 VGPR
// acc). Epilogue: 32KB LDS transpose in two 64-col chunks -> per-wave 1KB
// contiguous f32x4 stores (full 256B lines). Mask read once (pass 0), bits
// cached in u64 for pass 1. XCD batch pinning: z = bid & 7.
// ---------------------------------------------------------------------------
__global__ __launch_bounds__(256, 4) void scores_k(
    const unsigned short* __restrict__ P,
    const int* __restrict__ mask,
    float* __restrict__ out) {
  const int bid = blockIdx.x;
  const int z = bid & 7;             // batch == XCD slot (L2 locality)
  const int idx = bid >> 3;
  const int q0 = (idx >> 4) * 128, c0 = (idx & 15) * 128;
  const int tid = threadIdx.x;
  const int wave = tid >> 6, lane = tid & 63;
  const int wr = wave >> 1, wc = wave & 1;
  const int lr = lane & 15, kq = lane >> 4;

  __shared__ float lt[128 * 64];     // 32 KB

  const float rs = 0.08838834764831845f;  // 1/sqrt(128)
  unsigned long long mbits = 0ull;

  const size_t qrow = (size_t)(z * L_ + q0 + wr * 64) * D_;
  const size_t crow = (size_t)(z * L_ + c0 + wc * 64) * D_;

  for (int p = 0; p < 2; ++p) {      // p=0: mean (planes 0,1); p=1: std (2,3)
    const unsigned short* Qh = P + (size_t)(2 * p) * NP + qrow;
    const unsigned short* Ql = Qh + 4 * (size_t)NP;
    const unsigned short* Kh = P + (size_t)(2 * p + 1) * NP + crow;
    const unsigned short* Kl = Kh + 4 * (size_t)NP;

    f32x4 acc[4][4];
#pragma unroll
    for (int i = 0; i < 4; i++)
#pragma unroll
      for (int j = 0; j < 4; j++) acc[i][j] = f32x4{0.f, 0.f, 0.f, 0.f};

#pragma unroll
    for (int ks = 0; ks < 4; ks++) {
      const int koff = ks * 32 + kq * 8;
      short8 qh[4], ql[4];
#pragma unroll
      for (int t = 0; t < 4; t++) {
        const int ro = (t * 16 + lr) * D_ + koff;
        qh[t] = *(const short8*)(Qh + ro);
        ql[t] = *(const short8*)(Ql + ro);
      }
#pragma unroll
      for (int ni = 0; ni < 4; ni++) {
        const int ro = (ni * 16 + lr) * D_ + koff;
        short8 kh = *(const short8*)(Kh + ro);
        short8 kl = *(const short8*)(Kl + ro);
#pragma unroll
        for (int mi = 0; mi < 4; mi++) {
          acc[mi][ni] = __builtin_amdgcn_mfma_f32_16x16x32_bf16(qh[mi], kh, acc[mi][ni], 0, 0, 0);
          acc[mi][ni] = __builtin_amdgcn_mfma_f32_16x16x32_bf16(ql[mi], kh, acc[mi][ni], 0, 0, 0);
          acc[mi][ni] = __builtin_amdgcn_mfma_f32_16x16x32_bf16(qh[mi], kl, acc[mi][ni], 0, 0, 0);
        }
      }
    }

    // Epilogue: two 64-column chunks through 32KB LDS.
    for (int chunk = 0; chunk < 2; ++chunk) {
      if (wc == chunk) {
#pragma unroll
        for (int mi = 0; mi < 4; mi++)
#pragma unroll
          for (int r = 0; r < 4; r++) {
            const int row = wr * 64 + mi * 16 + kq * 4 + r;
            const int xr = ((row >> 2) & 3) << 4;   // 2-way max (free)
#pragma unroll
            for (int ni = 0; ni < 4; ni++)
              lt[row * 64 + ((ni * 16 + lr) ^ xr)] = acc[mi][ni][r];
          }
      }
      __syncthreads();
#pragma unroll
      for (int it = 0; it < 8; ++it) {
        const int di = it * 256 + tid;       // 0..2047
        const int row = di >> 4;             // 0..127
        const int c4 = (di & 15) * 4;        // 0..60, 16B aligned
        const int xr = ((row >> 2) & 3) << 4;
        f32x4 v = *(const f32x4*)&lt[row * 64 + (c4 ^ xr)];
        const size_t a = ((size_t)(z * L_ + q0 + row)) * L_ + c0 + chunk * 64 + c4;
        const int bbase = chunk * 32 + it * 4;
        f32x4 o;
        if (p == 0) {
          const int4 m4 = *(const int4*)&mask[a];
          const int mv[4] = {m4.x, m4.y, m4.z, m4.w};
#pragma unroll
          for (int j = 0; j < 4; j++) {
            float t = fast_tanh(v[j] * rs);
            o[j] = mv[j] ? (0.5f * t + 0.5f) : 0.0f;
            if (mv[j]) mbits |= (1ull << (bbase + j));
          }
          *(f32x4*)&out[a] = o;
        } else {
#pragma unroll
          for (int j = 0; j < 4; j++) {
            float t = fast_tanh(v[j] * rs);
            const bool mv = (mbits >> (bbase + j)) & 1ull;
            o[j] = mv ? (4.0f * t - 6.0f) : -10.0f;
          }
          *(f32x4*)&out[BLL + a] = o;
        }
      }
      __syncthreads();
    }
  }
}

extern "C" void kernel_launch(void* const* d_in, const int* in_sizes, int n_in,
                              void* d_out, int out_size, void* d_ws, size_t ws_size,
                              hipStream_t stream) {
  const float* query = (const float*)d_in[0];
  const float* key   = (const float*)d_in[1];
  const int*   mask  = (const int*)d_in[2];
  const float* Wqm   = (const float*)d_in[3];
  const float* bqm   = (const float*)d_in[4];
  const float* Wkm   = (const float*)d_in[5];
  const float* bkm   = (const float*)d_in[6];
  const float* Wqs   = (const float*)d_in[7];
  const float* bqs   = (const float*)d_in[8];
  const float* Wks   = (const float*)d_in[9];
  const float* bks   = (const float*)d_in[10];

  unsigned short* P  = (unsigned short*)d_ws;       // 8 * NP ushorts = 33.55 MB
  unsigned short* WT = P + 8 * (size_t)NP;          // 8 * 16384 ushorts
  unsigned short* XS = WT + 8 * 16384;              // 4 * NP ushorts = 16.8 MB

  prep_w<<<dim3(4, 64), 256, 0, stream>>>(Wqm, Wkm, Wqs, Wks, WT);
  split_x<<<dim3(2048), 256, 0, stream>>>(query, key, XS);
  proj_k<<<dim3(256, 2), 256, 0, stream>>>(XS, bqm, bkm, bqs, bks, WT, P);
  scores_k<<<dim3(2048), 256, 0, stream>>>(P, mask, (float*)d_out);
}

// Round 7
// 596.722 us; speedup vs baseline: 1.6276x; 1.0296x over previous
//
#include <hip/hip_runtime.h>

// GaussianActionDistGenerator: dual projection (mean/std) + masked tanh-clipped scores.
// B=8, L=2048, D=128. out = (s_mean [B,L,L], s_std [B,L,L]) f32, concatenated.

#define B_ 8
#define L_ 2048
#define D_ 128
#define NP (B_ * L_ * D_)            // 2,097,152 elems per projection array
#define BLL ((size_t)B_ * L_ * L_)   // 33,554,432 elems per output tensor

typedef __attribute__((ext_vector_type(8))) short short8;
typedef __attribute__((ext_vector_type(4))) float f32x4;
typedef __attribute__((ext_vector_type(4))) int i32x4;

__device__ __forceinline__ unsigned short f32_bf16(float x) {
  unsigned u = __float_as_uint(x);
  u += 0x7FFF + ((u >> 16) & 1);   // round-to-nearest-even on the bf16 boundary
  return (unsigned short)(u >> 16);
}
__device__ __forceinline__ float bf16_f32(unsigned short h) {
  return __uint_as_float(((unsigned)h) << 16);
}
__device__ __forceinline__ float fast_tanh(float x) {
  // tanh(x) = 1 - 2/(exp(2x)+1); saturates correctly at +/-inf
  float e = __expf(2.0f * x);
  return 1.0f - 2.0f * __builtin_amdgcn_rcpf(e + 1.0f);
}

// ---------------------------------------------------------------------------
// Kernel 0: transpose weights [k][n] -> [n][k] and split f32 -> bf16 hi/lo.
// ---------------------------------------------------------------------------
__global__ __launch_bounds__(256) void prep_w(
    const float* __restrict__ w0, const float* __restrict__ w1,
    const float* __restrict__ w2, const float* __restrict__ w3,
    unsigned short* __restrict__ WT) {
  int p = blockIdx.x;
  const float* W = (p == 0) ? w0 : (p == 1) ? w1 : (p == 2) ? w2 : w3;
  int idx = blockIdx.y * 256 + threadIdx.x;   // 0..16383 = k*128+n
  int k = idx >> 7, n = idx & 127;
  float v = W[idx];
  unsigned short h = f32_bf16(v);
  WT[p * 16384 + n * 128 + k] = h;
  WT[(4 + p) * 16384 + n * 128 + k] = f32_bf16(v - bf16_f32(h));
}

// ---------------------------------------------------------------------------
// Kernel 0b: split query/key f32 -> bf16 hi/lo planes, fully coalesced.
// XS layout (ushort): [query_hi NP][query_lo NP][key_hi NP][key_lo NP]
// ---------------------------------------------------------------------------
__global__ __launch_bounds__(256) void split_x(
    const float* __restrict__ q, const float* __restrict__ k,
    unsigned short* __restrict__ XS) {
  size_t idx = ((size_t)blockIdx.x * 256 + threadIdx.x) * 8;
  const float* src;
  unsigned short* dh;
  if (idx < (size_t)NP) {
    src = q + idx;
    dh = XS + idx;
  } else {
    src = k + (idx - NP);
    dh = XS + 2 * (size_t)NP + (idx - NP);
  }
  unsigned short* dl = dh + NP;
  f32x4 v0 = *(const f32x4*)src;
  f32x4 v1 = *(const f32x4*)(src + 4);
  short8 h, l;
#pragma unroll
  for (int j = 0; j < 4; j++) {
    unsigned short hh = f32_bf16(v0[j]);
    h[j] = (short)hh;
    l[j] = (short)f32_bf16(v0[j] - bf16_f32(hh));
    unsigned short hg = f32_bf16(v1[j]);
    h[4 + j] = (short)hg;
    l[4 + j] = (short)f32_bf16(v1[j] - bf16_f32(hg));
  }
  *(short8*)dh = h;
  *(short8*)dl = l;
}

// ---------------------------------------------------------------------------
// Kernel 1: projections. y=0: query -> qm (p0), qs (p2); y=1: key -> km, ks.
// MFMA 16x16x32 bf16, hi/lo 3-product split. A from pre-split XS.
// Output P (ushort): P[p*NP + token*128 + d] hi, P[(4+p)*NP + ...] lo.
// ---------------------------------------------------------------------------
__global__ __launch_bounds__(256) void proj_k(
    const unsigned short* __restrict__ XS,
    const float* __restrict__ bqm, const float* __restrict__ bkm,
    const float* __restrict__ bqs, const float* __restrict__ bks,
    const unsigned short* __restrict__ WT,
    unsigned short* __restrict__ P) {
  const int y = blockIdx.y;
  const unsigned short* Xh = XS + (size_t)y * 2 * NP;
  const unsigned short* Xl = Xh + NP;
  const float* bias_m = y ? bkm : bqm;
  const float* bias_s = y ? bks : bqs;
  const int pm = y, ps = y + 2;
  const int wave = threadIdx.x >> 6, lane = threadIdx.x & 63;
  const int lr = lane & 15, kq = lane >> 4;
  const int rowbase = blockIdx.x * 64 + wave * 16;

  const unsigned short* wmh = WT + pm * 16384;
  const unsigned short* wml = WT + (4 + pm) * 16384;
  const unsigned short* wsh = WT + ps * 16384;
  const unsigned short* wsl = WT + (4 + ps) * 16384;

  f32x4 accm[8], accs[8];
#pragma unroll
  for (int i = 0; i < 8; i++) {
    accm[i] = f32x4{0.f, 0.f, 0.f, 0.f};
    accs[i] = f32x4{0.f, 0.f, 0.f, 0.f};
  }

#pragma unroll
  for (int ks = 0; ks < 4; ks++) {
    const int koff = ks * 32 + kq * 8;
    const int ao = (rowbase + lr) * D_ + koff;
    short8 a_hi = *(const short8*)(Xh + ao);
    short8 a_lo = *(const short8*)(Xl + ao);
#pragma unroll
    for (int nt = 0; nt < 8; nt++) {
      const int wo = (nt * 16 + lr) * 128 + koff;
      short8 bh = *(const short8*)(wmh + wo);
      short8 bl = *(const short8*)(wml + wo);
      accm[nt] = __builtin_amdgcn_mfma_f32_16x16x32_bf16(a_hi, bh, accm[nt], 0, 0, 0);
      accm[nt] = __builtin_amdgcn_mfma_f32_16x16x32_bf16(a_lo, bh, accm[nt], 0, 0, 0);
      accm[nt] = __builtin_amdgcn_mfma_f32_16x16x32_bf16(a_hi, bl, accm[nt], 0, 0, 0);
      short8 ch = *(const short8*)(wsh + wo);
      short8 cl = *(const short8*)(wsl + wo);
      accs[nt] = __builtin_amdgcn_mfma_f32_16x16x32_bf16(a_hi, ch, accs[nt], 0, 0, 0);
      accs[nt] = __builtin_amdgcn_mfma_f32_16x16x32_bf16(a_lo, ch, accs[nt], 0, 0, 0);
      accs[nt] = __builtin_amdgcn_mfma_f32_16x16x32_bf16(a_hi, cl, accs[nt], 0, 0, 0);
    }
  }

  unsigned short* Pmh = P + pm * NP;
  unsigned short* Pml = P + (4 + pm) * NP;
  unsigned short* Psh = P + ps * NP;
  unsigned short* Psl = P + (4 + ps) * NP;
#pragma unroll
  for (int nt = 0; nt < 8; nt++) {
    const int col = nt * 16 + lr;
    const float bm = bias_m[col];
    const float bs = bias_s[col];
#pragma unroll
    for (int r = 0; r < 4; r++) {
      const int token = rowbase + kq * 4 + r;
      const int o = token * D_ + col;
      float vm = accm[nt][r] + bm;
      unsigned short h = f32_bf16(vm);
      Pmh[o] = h;
      Pml[o] = f32_bf16(vm - bf16_f32(h));
      float vs = accs[nt][r] + bs;
      unsigned short g = f32_bf16(vs);
      Psh[o] = g;
      Psl[o] = f32_bf16(vs - bf16_f32(g));
    }
  }
}

// ---------------------------------------------------------------------------
// Kernel 2 (v5): masked scores, row-panel tiling.
// Block = 16 q-rows x FULL 2048 cols of one batch; grid 1024 (z = bid&7 pins
// batch -> XCD; K hi-panels 1 MB/batch stay L2-resident). Asymmetric 2-term
// split: S = (qh+ql)*kh (K lo-planes never read). Per col-chunk of 256 (wave
// owns 64 cols): MFMA -> 16KB LDS transpose -> nontemporal int4 mask loads
// and f32x4 out stores (1KB contiguous per wave; no L2 write-allocate).
// Mask bits cached per chunk in a u32 for the std pass.
// ---------------------------------------------------------------------------
__global__ __launch_bounds__(256, 4) void scores_k(
    const unsigned short* __restrict__ P,
    const int* __restrict__ mask,
    float* __restrict__ out) {
  const int bid = blockIdx.x;
  const int z = bid & 7;             // batch == XCD slot (L2 locality)
  const int q0 = (bid >> 3) * 16;    // 0..2032
  const int tid = threadIdx.x;
  const int wave = tid >> 6, lane = tid & 63;
  const int lr = lane & 15, kq = lane >> 4;

  __shared__ float tb[16 * 256];     // 16 KB transpose buffer

  const float rs = 0.08838834764831845f;  // 1/sqrt(128)

  const size_t qbase = (size_t)(z * L_ + q0) * D_;
  const size_t kbase = (size_t)(z * L_) * D_;
  const unsigned short* Qmh = P + 0 * (size_t)NP + qbase;
  const unsigned short* Qml = P + 4 * (size_t)NP + qbase;
  const unsigned short* Qsh = P + 2 * (size_t)NP + qbase;
  const unsigned short* Qsl = P + 6 * (size_t)NP + qbase;
  const unsigned short* Kmh = P + 1 * (size_t)NP + kbase;
  const unsigned short* Ksh = P + 3 * (size_t)NP + kbase;

  for (int cc = 0; cc < 8; ++cc) {           // column chunks of 256
    const int colb = cc * 256 + wave * 64;   // this wave's 64 columns

    f32x4 am[4], as_[4];
#pragma unroll
    for (int i = 0; i < 4; i++) {
      am[i] = f32x4{0.f, 0.f, 0.f, 0.f};
      as_[i] = f32x4{0.f, 0.f, 0.f, 0.f};
    }

#pragma unroll
    for (int ks = 0; ks < 4; ks++) {
      const int ko = ks * 32 + kq * 8;
      const int ao = lr * D_ + ko;
      short8 qmh = *(const short8*)(Qmh + ao);
      short8 qml = *(const short8*)(Qml + ao);
      short8 qsh = *(const short8*)(Qsh + ao);
      short8 qsl = *(const short8*)(Qsl + ao);
#pragma unroll
      for (int ni = 0; ni < 4; ni++) {
        const int ro = (colb + ni * 16 + lr) * D_ + ko;
        short8 bm = *(const short8*)(Kmh + ro);
        short8 bs = *(const short8*)(Ksh + ro);
        am[ni] = __builtin_amdgcn_mfma_f32_16x16x32_bf16(qmh, bm, am[ni], 0, 0, 0);
        am[ni] = __builtin_amdgcn_mfma_f32_16x16x32_bf16(qml, bm, am[ni], 0, 0, 0);
        as_[ni] = __builtin_amdgcn_mfma_f32_16x16x32_bf16(qsh, bs, as_[ni], 0, 0, 0);
        as_[ni] = __builtin_amdgcn_mfma_f32_16x16x32_bf16(qsl, bs, as_[ni], 0, 0, 0);
      }
    }

    // ---- mean: transpose -> masked nt-store; cache mask bits ----
#pragma unroll
    for (int ni = 0; ni < 4; ni++)
#pragma unroll
      for (int r = 0; r < 4; r++) {
        const int row = kq * 4 + r;
        const int col = wave * 64 + ni * 16 + lr;
        tb[row * 256 + (col ^ (kq << 4))] = am[ni][r];   // 2-way max (free)
      }
    __syncthreads();

    unsigned mb = 0;
#pragma unroll
    for (int it = 0; it < 4; ++it) {
      const int idx = it * 256 + tid;      // 0..1023
      const int row = idx >> 6;            // 0..15
      const int c4 = (idx & 63) * 4;       // 0..252
      f32x4 v = *(const f32x4*)&tb[row * 256 + (c4 ^ ((row >> 2) << 4))];
      const size_t a = ((size_t)(z * L_ + q0 + row)) * L_ + cc * 256 + c4;
      i32x4 m4 = __builtin_nontemporal_load((const i32x4*)&mask[a]);
      f32x4 o;
#pragma unroll
      for (int j = 0; j < 4; j++) {
        float t = fast_tanh(v[j] * rs);
        o[j] = m4[j] ? (0.5f * t + 0.5f) : 0.0f;
        if (m4[j]) mb |= (1u << (it * 4 + j));
      }
      __builtin_nontemporal_store(o, (f32x4*)&out[a]);
    }
    __syncthreads();

    // ---- std: transpose -> masked nt-store using cached bits ----
#pragma unroll
    for (int ni = 0; ni < 4; ni++)
#pragma unroll
      for (int r = 0; r < 4; r++) {
        const int row = kq * 4 + r;
        const int col = wave * 64 + ni * 16 + lr;
        tb[row * 256 + (col ^ (kq << 4))] = as_[ni][r];
      }
    __syncthreads();

#pragma unroll
    for (int it = 0; it < 4; ++it) {
      const int idx = it * 256 + tid;
      const int row = idx >> 6;
      const int c4 = (idx & 63) * 4;
      f32x4 v = *(const f32x4*)&tb[row * 256 + (c4 ^ ((row >> 2) << 4))];
      const size_t a = ((size_t)(z * L_ + q0 + row)) * L_ + cc * 256 + c4;
      f32x4 o;
#pragma unroll
      for (int j = 0; j < 4; j++) {
        float t = fast_tanh(v[j] * rs);
        const bool mv = (mb >> (it * 4 + j)) & 1u;
        o[j] = mv ? (4.0f * t - 6.0f) : -10.0f;
      }
      __builtin_nontemporal_store(o, (f32x4*)&out[BLL + a]);
    }
    __syncthreads();
  }
}

extern "C" void kernel_launch(void* const* d_in, const int* in_sizes, int n_in,
                              void* d_out, int out_size, void* d_ws, size_t ws_size,
                              hipStream_t stream) {
  const float* query = (const float*)d_in[0];
  const float* key   = (const float*)d_in[1];
  const int*   mask  = (const int*)d_in[2];
  const float* Wqm   = (const float*)d_in[3];
  const float* bqm   = (const float*)d_in[4];
  const float* Wkm   = (const float*)d_in[5];
  const float* bkm   = (const float*)d_in[6];
  const float* Wqs   = (const float*)d_in[7];
  const float* bqs   = (const float*)d_in[8];
  const float* Wks   = (const float*)d_in[9];
  const float* bks   = (const float*)d_in[10];

  unsigned short* P  = (unsigned short*)d_ws;       // 8 * NP ushorts = 33.55 MB
  unsigned short* WT = P + 8 * (size_t)NP;          // 8 * 16384 ushorts
  unsigned short* XS = WT + 8 * 16384;              // 4 * NP ushorts = 16.8 MB

  prep_w<<<dim3(4, 64), 256, 0, stream>>>(Wqm, Wkm, Wqs, Wks, WT);
  split_x<<<dim3(2048), 256, 0, stream>>>(query, key, XS);
  proj_k<<<dim3(256, 2), 256, 0, stream>>>(XS, bqm, bkm, bqs, bks, WT, P);
  scores_k<<<dim3(1024), 256, 0, stream>>>(P, mask, (float*)d_out);
}